// Round 4
// baseline (466.790 us; speedup 1.0000x reference)
//
#include <hip/hip_runtime.h>
#include <hip/hip_cooperative_groups.h>
#include <cstdint>
#include <cstddef>

namespace cg = cooperative_groups;

#define NN 4096
#define FDIM 256

typedef __attribute__((ext_vector_type(4))) float fx4;
typedef __attribute__((ext_vector_type(2))) float fx2;
typedef __attribute__((ext_vector_type(8))) short s8v;

__device__ inline uint16_t f2bf(float f) {
    union { float f; uint32_t u; } v; v.f = f;
    uint32_t u = v.u;
    uint32_t r = (u + 0x7FFFu + ((u >> 16) & 1u)) >> 16;
    return (uint16_t)r;
}

union SMem {
    struct { float xs[2 * 64 * 34]; float wt[2 * 64 * 68]; } p1;             // 52224 B
    struct { float E1s[NN]; float E2s[NN]; float red1[4], red2[4];
             int wtot[4]; int base_s; } p3;                                   // ~32.8 KB
    struct { float tile[32 * 65]; } p4;                                       // 8.3 KB
    struct { uint16_t As[64 * 72]; uint16_t Gs[272 * 72]; } p5;               // 48384 B
};

// =================== single cooperative mega-kernel ===================
__global__ __launch_bounds__(256, 2) void k_mega(
        const float* __restrict__ x, const int* __restrict__ adj,
        const float* __restrict__ W, const float* __restrict__ bias,
        const float* __restrict__ att_w,
        float* __restrict__ h, uint16_t* __restrict__ gt,
        float* __restrict__ a1, float* __restrict__ a2,
        float* __restrict__ E1, float* __restrict__ E2,
        float* __restrict__ wraw, float* __restrict__ Sg,
        float* __restrict__ part, float* __restrict__ out) {
    cg::grid_group grid = cg::this_grid();
    __shared__ SMem sm;
    const int blk = blockIdx.x;
    const int t = threadIdx.x;
    const int lane = t & 63, wv = t >> 6;

    // ---------------- Phase 1: h = x @ W.T + b (dbuf + reg prefetch) ----------------
    {
        const int bi = blk & 127, bf = blk >> 7;
        const int tx = t & 15, ty = t >> 4;
        float acc[2][4] = {};
        float rx[8], rw[16];
        #pragma unroll
        for (int u = 0; u < 8; ++u) {
            const int e = t + 256 * u, r = e >> 6, c = e & 63;
            rx[u] = x[(size_t)(bi * 32 + r) * 256 + c];
        }
        #pragma unroll
        for (int u = 0; u < 16; ++u) {
            const int e = t + 256 * u, r = e >> 6, c = e & 63;
            rw[u] = W[(size_t)(bf * 64 + r) * 256 + c];
        }
        for (int p = 0; p < 4; ++p) {
            float* xb = sm.p1.xs + (p & 1) * (64 * 34);
            float* wb = sm.p1.wt + (p & 1) * (64 * 68);
            #pragma unroll
            for (int u = 0; u < 8; ++u) {
                const int e = t + 256 * u, r = e >> 6, c = e & 63;
                xb[c * 34 + r] = rx[u];
            }
            #pragma unroll
            for (int u = 0; u < 16; ++u) {
                const int e = t + 256 * u, r = e >> 6, c = e & 63;
                const int sw = 8 * ((c & 7) ^ ((c >> 3) & 7));
                wb[c * 68 + (r ^ sw)] = rw[u];
            }
            __syncthreads();
            if (p < 3) {
                const int k0 = (p + 1) * 64;
                #pragma unroll
                for (int u = 0; u < 8; ++u) {
                    const int e = t + 256 * u, r = e >> 6, c = e & 63;
                    rx[u] = x[(size_t)(bi * 32 + r) * 256 + k0 + c];
                }
                #pragma unroll
                for (int u = 0; u < 16; ++u) {
                    const int e = t + 256 * u, r = e >> 6, c = e & 63;
                    rw[u] = W[(size_t)(bf * 64 + r) * 256 + k0 + c];
                }
            }
            #pragma unroll 16
            for (int k = 0; k < 64; ++k) {
                const int sw = 8 * ((k & 7) ^ ((k >> 3) & 7));
                const fx2 av = *(const fx2*)(xb + k * 34 + ty * 2);
                const fx4 bv = *(const fx4*)(wb + k * 68 + ((tx * 4) ^ sw));
                #pragma unroll
                for (int u = 0; u < 2; ++u)
                    #pragma unroll
                    for (int v = 0; v < 4; ++v)
                        acc[u][v] += av[u] * bv[v];
            }
        }
        const fx4 bv = *(const fx4*)(bias + bf * 64 + tx * 4);
        #pragma unroll
        for (int u = 0; u < 2; ++u) {
            const int i = bi * 32 + ty * 2 + u;
            fx4 r;
            #pragma unroll
            for (int v = 0; v < 4; ++v) r[v] = acc[u][v] + bv[v];
            *(fx4*)(h + (size_t)i * 256 + bf * 64 + tx * 4) = r;
        }
    }
    grid.sync();

    // ---------------- Phase 2: a1 = h@w1, a2 = h@w2 (8 rows/block) ----------------
    {
        const fx4 w1v = *(const fx4*)(att_w + lane * 4);
        const fx4 w2v = *(const fx4*)(att_w + 256 + lane * 4);
        #pragma unroll
        for (int u = 0; u < 2; ++u) {
            const int row = blk * 8 + wv * 2 + u;
            const fx4 hv = *(const fx4*)(h + (size_t)row * 256 + lane * 4);
            float s1 = hv[0] * w1v[0] + hv[1] * w1v[1] + hv[2] * w1v[2] + hv[3] * w1v[3];
            float s2 = hv[0] * w2v[0] + hv[1] * w2v[1] + hv[2] * w2v[2] + hv[3] * w2v[3];
            #pragma unroll
            for (int d = 32; d > 0; d >>= 1) {
                s1 += __shfl_down(s1, d);
                s2 += __shfl_down(s2, d);
            }
            if (lane == 0) { a1[row] = s1; a2[row] = s2; }
        }
    }
    grid.sync();

    // ---------------- Phase 3: max/exp + Sg=0 + edge scan (block 0 only) ----------------
    if (blk == 0) {
        fx4 va1[4], va2[4];
        #pragma unroll
        for (int j = 0; j < 4; ++j) {
            va1[j] = *(const fx4*)(a1 + t * 16 + j * 4);
            va2[j] = *(const fx4*)(a2 + t * 16 + j * 4);
        }
        float m1 = -1e30f, m2 = -1e30f;
        #pragma unroll
        for (int j = 0; j < 4; ++j)
            #pragma unroll
            for (int k = 0; k < 4; ++k) {
                m1 = fmaxf(m1, va1[j][k]);
                m2 = fmaxf(m2, va2[j][k]);
            }
        #pragma unroll
        for (int d = 32; d > 0; d >>= 1) {
            m1 = fmaxf(m1, __shfl_down(m1, d));
            m2 = fmaxf(m2, __shfl_down(m2, d));
        }
        if (lane == 0) { sm.p3.red1[wv] = m1; sm.p3.red2[wv] = m2; }
        __syncthreads();
        const float M1 = fmaxf(fmaxf(sm.p3.red1[0], sm.p3.red1[1]),
                               fmaxf(sm.p3.red1[2], sm.p3.red1[3]));
        const float M2 = fmaxf(fmaxf(sm.p3.red2[0], sm.p3.red2[1]),
                               fmaxf(sm.p3.red2[2], sm.p3.red2[3]));
        const fx4 z4 = {0.f, 0.f, 0.f, 0.f};
        #pragma unroll
        for (int j = 0; j < 4; ++j) {
            fx4 e1v, e2v;
            #pragma unroll
            for (int k = 0; k < 4; ++k) {
                e1v[k] = expf(va1[j][k] - M1);
                e2v[k] = expf(va2[j][k] - M2);
            }
            *(fx4*)(sm.p3.E1s + t * 16 + j * 4) = e1v;
            *(fx4*)(sm.p3.E2s + t * 16 + j * 4) = e2v;
            *(fx4*)(E1 + t * 16 + j * 4) = e1v;
            *(fx4*)(E2 + t * 16 + j * 4) = e2v;
            *(fx4*)(wraw + t * 16 + j * 4) = z4;
        }
        if (t == 0) { *Sg = 0.f; sm.p3.base_s = 0; }
        __syncthreads();
        for (int row = 0; row < NN; ++row) {
            const int base = sm.p3.base_s;     // uniform
            if (base >= NN) break;             // uniform break
            const int* arow = adj + (size_t)row * NN + t * 16;
            const int4 A0 = ((const int4*)arow)[0];
            const int4 A1 = ((const int4*)arow)[1];
            const int4 A2 = ((const int4*)arow)[2];
            const int4 A3 = ((const int4*)arow)[3];
            const int v[16] = {A0.x, A0.y, A0.z, A0.w, A1.x, A1.y, A1.z, A1.w,
                               A2.x, A2.y, A2.z, A2.w, A3.x, A3.y, A3.z, A3.w};
            int cnt = 0;
            #pragma unroll
            for (int j = 0; j < 16; ++j) cnt += (v[j] == 1);
            int inc = cnt;
            #pragma unroll
            for (int d = 1; d < 64; d <<= 1) {
                const int y = __shfl_up(inc, d);
                if (lane >= d) inc += y;
            }
            if (lane == 63) sm.p3.wtot[wv] = inc;
            __syncthreads();                   // B1
            int wbase = 0, total = 0;
            #pragma unroll
            for (int w = 0; w < 4; ++w) {
                const int xw = sm.p3.wtot[w];
                total += xw;
                wbase += (w < wv) ? xw : 0;
            }
            if (t == 0) sm.p3.base_s = base + total;
            int r = base + wbase + inc - cnt;
            if (cnt && r < NN) {
                const float e1 = sm.p3.E1s[row];
                #pragma unroll
                for (int j = 0; j < 16; ++j) {
                    if (v[j] == 1) {
                        if (r < NN) wraw[r] = e1 * sm.p3.E2s[t * 16 + j];
                        ++r;
                    }
                }
            }
            __syncthreads();                   // B2
        }
    }
    grid.sync();

    // ---------------- Phase 4: gt[f][j] = bf16(wraw[j]*h[j][f]) ----------------
    {
        const int bj = blk & 127, bf = blk >> 7;   // 128 j-tiles(32) x 4 f-tiles(64)
        const int j0 = bj * 32, f0 = bf * 64;
        #pragma unroll
        for (int p = 0; p < 8; ++p) {
            const int e = t + 256 * p;
            const int jl = e >> 6, fl = e & 63;
            sm.p4.tile[jl * 65 + fl] =
                h[(size_t)(j0 + jl) * 256 + f0 + fl] * wraw[j0 + jl];
        }
        __syncthreads();
        #pragma unroll
        for (int p = 0; p < 8; ++p) {
            const int e = t + 256 * p;
            const int fl = e >> 5, jl = e & 31;
            gt[(size_t)(f0 + fl) * NN + j0 + jl] = f2bf(sm.p4.tile[jl * 65 + fl]);
        }
    }
    grid.sync();

    // ---------------- Phase 5: part = A @ G (bf16 MFMA, splitk=8) + S-column ----------------
    {
        const int ib = blk & 63, ks = blk >> 6;
        const int q = lane >> 4, m16 = lane & 15;
        const int i0 = ib * 64, k0 = ks * 512;
        fx4 acc[4][4];
        #pragma unroll
        for (int a = 0; a < 4; ++a)
            #pragma unroll
            for (int b = 0; b < 4; ++b) acc[a][b] = (fx4){0.f, 0.f, 0.f, 0.f};
        fx4 accS[4];
        #pragma unroll
        for (int a = 0; a < 4; ++a) accS[a] = (fx4){0.f, 0.f, 0.f, 0.f};
        // zero Gs rows 257..271 once (covered by first in-loop barrier)
        for (int e = t; e < 15 * 72; e += 256) sm.p5.Gs[257 * 72 + e] = 0;
        for (int step = 0; step < 8; ++step) {
            const int kk = k0 + step * 64;
            #pragma unroll
            for (int p = 0; p < 4; ++p) {
                const int r = p * 16 + (t >> 4);
                const int c4 = (t & 15) * 4;
                const int4 a = *(const int4*)(adj + (size_t)(i0 + r) * NN + kk + c4);
                uint2 w;
                w.x = (uint32_t)(a.x | (a.y << 16)) * 0x3F80u;
                w.y = (uint32_t)(a.z | (a.w << 16)) * 0x3F80u;
                *(uint2*)(&sm.p5.As[r * 72 + c4]) = w;
            }
            #pragma unroll
            for (int p = 0; p < 8; ++p) {
                const int f = p * 32 + (t >> 3);
                const int ch = (t & 7) * 8;
                const s8v v = *(const s8v*)(gt + (size_t)f * NN + kk + ch);
                *(s8v*)(sm.p5.Gs + f * 72 + ch) = v;
            }
            if (t < 8) {
                const float* e2p = E2 + kk + t * 8;
                uint32_t* dst = (uint32_t*)(&sm.p5.Gs[256 * 72 + t * 8]);
                #pragma unroll
                for (int j = 0; j < 4; ++j)
                    dst[j] = (uint32_t)f2bf(e2p[2 * j]) |
                             ((uint32_t)f2bf(e2p[2 * j + 1]) << 16);
            }
            __syncthreads();
            s8v afr[4][2];
            #pragma unroll
            for (int it = 0; it < 4; ++it)
                #pragma unroll
                for (int kh = 0; kh < 2; ++kh)
                    afr[it][kh] = *(const s8v*)(sm.p5.As + (it * 16 + m16) * 72 + kh * 32 + q * 8);
            #pragma unroll
            for (int ft = 0; ft < 4; ++ft) {
                #pragma unroll
                for (int kh = 0; kh < 2; ++kh) {
                    const s8v bfr = *(const s8v*)(sm.p5.Gs + (wv * 64 + ft * 16 + m16) * 72 + kh * 32 + q * 8);
                    #pragma unroll
                    for (int it = 0; it < 4; ++it)
                        acc[it][ft] = __builtin_amdgcn_mfma_f32_16x16x32_bf16(
                            afr[it][kh], bfr, acc[it][ft], 0, 0, 0);
                }
            }
            if (wv == 3) {
                #pragma unroll
                for (int kh = 0; kh < 2; ++kh) {
                    const s8v bfrS = *(const s8v*)(sm.p5.Gs + (256 + m16) * 72 + kh * 32 + q * 8);
                    #pragma unroll
                    for (int it = 0; it < 4; ++it)
                        accS[it] = __builtin_amdgcn_mfma_f32_16x16x32_bf16(
                            afr[it][kh], bfrS, accS[it], 0, 0, 0);
                }
            }
            __syncthreads();
        }
        if (wv == 3) {
            float s_local = 0.f;
            #pragma unroll
            for (int it = 0; it < 4; ++it)
                #pragma unroll
                for (int r = 0; r < 4; ++r)
                    s_local += accS[it][r] * E1[i0 + it * 16 + q * 4 + r];
            #pragma unroll
            for (int d = 32; d > 0; d >>= 1) s_local += __shfl_down(s_local, d);
            if (lane == 0) atomicAdd(Sg, s_local);
        }
        float* dst = part + (size_t)ks * NN * FDIM;
        #pragma unroll
        for (int it = 0; it < 4; ++it) {
            #pragma unroll
            for (int ft = 0; ft < 4; ++ft) {
                const int f = wv * 64 + ft * 16 + m16;
                #pragma unroll
                for (int r = 0; r < 4; ++r) {
                    const int i = i0 + it * 16 + q * 4 + r;
                    dst[(size_t)i * FDIM + f] = acc[it][ft][r];
                }
            }
        }
    }
    grid.sync();

    // ---------------- Phase 6: out = relu(sum_k part_k) / S ----------------
    {
        const float Sv = *(volatile const float*)Sg;
        const float inv = 1.0f / Sv;
        #pragma unroll
        for (int rep = 0; rep < 2; ++rep) {
            const size_t idx = (size_t)blk * 2048 + rep * 1024 + t * 4;
            fx4 s = {0.f, 0.f, 0.f, 0.f};
            #pragma unroll
            for (int k = 0; k < 8; ++k)
                s += *(const fx4*)(part + (size_t)k * NN * FDIM + idx);
            fx4 r;
            r[0] = fmaxf(s[0], 0.f) * inv;
            r[1] = fmaxf(s[1], 0.f) * inv;
            r[2] = fmaxf(s[2], 0.f) * inv;
            r[3] = fmaxf(s[3], 0.f) * inv;
            *(fx4*)(out + idx) = r;
        }
    }
}

// =================== fallback path (round-3 kernels) ===================
__global__ __launch_bounds__(256) void k_h(const float* __restrict__ x,
        const float* __restrict__ W, const float* __restrict__ bias,
        float* __restrict__ h) {
    __shared__ __align__(16) float xs[2][64 * 34];
    __shared__ __align__(16) float wt[2][64 * 68];
    const int bi = blockIdx.x, bf = blockIdx.y;
    const int t = threadIdx.x;
    const int tx = t & 15, ty = t >> 4;
    float acc[2][4] = {};
    float rx[8], rw[16];
    #pragma unroll
    for (int u = 0; u < 8; ++u) {
        const int e = t + 256 * u, r = e >> 6, c = e & 63;
        rx[u] = x[(size_t)(bi * 32 + r) * 256 + c];
    }
    #pragma unroll
    for (int u = 0; u < 16; ++u) {
        const int e = t + 256 * u, r = e >> 6, c = e & 63;
        rw[u] = W[(size_t)(bf * 64 + r) * 256 + c];
    }
    for (int p = 0; p < 4; ++p) {
        float* xb = xs[p & 1];
        float* wb = wt[p & 1];
        #pragma unroll
        for (int u = 0; u < 8; ++u) {
            const int e = t + 256 * u, r = e >> 6, c = e & 63;
            xb[c * 34 + r] = rx[u];
        }
        #pragma unroll
        for (int u = 0; u < 16; ++u) {
            const int e = t + 256 * u, r = e >> 6, c = e & 63;
            const int sw = 8 * ((c & 7) ^ ((c >> 3) & 7));
            wb[c * 68 + (r ^ sw)] = rw[u];
        }
        __syncthreads();
        if (p < 3) {
            const int k0 = (p + 1) * 64;
            #pragma unroll
            for (int u = 0; u < 8; ++u) {
                const int e = t + 256 * u, r = e >> 6, c = e & 63;
                rx[u] = x[(size_t)(bi * 32 + r) * 256 + k0 + c];
            }
            #pragma unroll
            for (int u = 0; u < 16; ++u) {
                const int e = t + 256 * u, r = e >> 6, c = e & 63;
                rw[u] = W[(size_t)(bf * 64 + r) * 256 + k0 + c];
            }
        }
        #pragma unroll 16
        for (int k = 0; k < 64; ++k) {
            const int sw = 8 * ((k & 7) ^ ((k >> 3) & 7));
            const fx2 av = *(const fx2*)(xb + k * 34 + ty * 2);
            const fx4 bv = *(const fx4*)(wb + k * 68 + ((tx * 4) ^ sw));
            #pragma unroll
            for (int u = 0; u < 2; ++u)
                #pragma unroll
                for (int v = 0; v < 4; ++v)
                    acc[u][v] += av[u] * bv[v];
        }
    }
    const fx4 bv = *(const fx4*)(bias + bf * 64 + tx * 4);
    #pragma unroll
    for (int u = 0; u < 2; ++u) {
        const int i = bi * 32 + ty * 2 + u;
        fx4 r;
        #pragma unroll
        for (int v = 0; v < 4; ++v) r[v] = acc[u][v] + bv[v];
        *(fx4*)(h + (size_t)i * 256 + bf * 64 + tx * 4) = r;
    }
}

__global__ __launch_bounds__(256) void k_a(const float* __restrict__ h,
        const float* __restrict__ att_w, float* __restrict__ a1,
        float* __restrict__ a2) {
    const int wv = threadIdx.x >> 6, l = threadIdx.x & 63;
    const int i = blockIdx.x * 4 + wv;
    float s1 = 0.f, s2 = 0.f;
    #pragma unroll
    for (int c = l; c < 256; c += 64) {
        const float hv = h[(size_t)i * 256 + c];
        s1 += hv * att_w[c];
        s2 += hv * att_w[256 + c];
    }
    #pragma unroll
    for (int d = 32; d > 0; d >>= 1) {
        s1 += __shfl_down(s1, d);
        s2 += __shfl_down(s2, d);
    }
    if (l == 0) { a1[i] = s1; a2[i] = s2; }
}

__global__ __launch_bounds__(1024) void k_prep(const float* __restrict__ a1,
        const float* __restrict__ a2, const int* __restrict__ adj,
        float* __restrict__ E1, float* __restrict__ E2,
        float* __restrict__ wraw, float* __restrict__ Sg) {
    __shared__ float E1s[NN];
    __shared__ float E2s[NN];
    __shared__ float red1[16], red2[16];
    __shared__ int wtot[16];
    __shared__ int base_s;
    const int t = threadIdx.x, lane = t & 63, wv = t >> 6;
    const fx4 v1 = *(const fx4*)(a1 + t * 4);
    const fx4 v2 = *(const fx4*)(a2 + t * 4);
    float m1 = fmaxf(fmaxf(v1[0], v1[1]), fmaxf(v1[2], v1[3]));
    float m2 = fmaxf(fmaxf(v2[0], v2[1]), fmaxf(v2[2], v2[3]));
    #pragma unroll
    for (int d = 32; d > 0; d >>= 1) {
        m1 = fmaxf(m1, __shfl_down(m1, d));
        m2 = fmaxf(m2, __shfl_down(m2, d));
    }
    if (lane == 0) { red1[wv] = m1; red2[wv] = m2; }
    __syncthreads();
    if (t == 0) {
        float mm1 = -1e30f, mm2 = -1e30f;
        for (int k = 0; k < 16; ++k) {
            mm1 = fmaxf(mm1, red1[k]);
            mm2 = fmaxf(mm2, red2[k]);
        }
        red1[0] = mm1; red2[0] = mm2;
        *Sg = 0.f;
        base_s = 0;
    }
    __syncthreads();
    const float M1 = red1[0], M2 = red2[0];
    fx4 e1v, e2v, z4 = {0.f, 0.f, 0.f, 0.f};
    #pragma unroll
    for (int j = 0; j < 4; ++j) {
        e1v[j] = expf(v1[j] - M1);
        e2v[j] = expf(v2[j] - M2);
    }
    *(fx4*)(E1s + t * 4) = e1v;
    *(fx4*)(E2s + t * 4) = e2v;
    *(fx4*)(E1 + t * 4) = e1v;
    *(fx4*)(E2 + t * 4) = e2v;
    *(fx4*)(wraw + t * 4) = z4;
    __syncthreads();
    for (int row = 0; row < NN; ++row) {
        const int base = base_s;
        if (base >= NN) break;
        const int4 a = ((const int4*)(adj + (size_t)row * NN))[t];
        const int vj[4] = {a.x, a.y, a.z, a.w};
        int cnt = 0;
        #pragma unroll
        for (int j = 0; j < 4; ++j) cnt += (vj[j] == 1);
        int inc = cnt;
        #pragma unroll
        for (int d = 1; d < 64; d <<= 1) {
            const int y = __shfl_up(inc, d);
            if (lane >= d) inc += y;
        }
        if (lane == 63) wtot[wv] = inc;
        __syncthreads();
        int wbase = 0, total = 0;
        #pragma unroll
        for (int w = 0; w < 16; ++w) {
            const int xw = wtot[w];
            total += xw;
            wbase += (w < wv) ? xw : 0;
        }
        if (t == 0) base_s = base + total;
        int r = base + wbase + inc - cnt;
        if (cnt && r < NN) {
            const float e1 = E1s[row];
            #pragma unroll
            for (int j = 0; j < 4; ++j) {
                if (vj[j] == 1) {
                    if (r < NN) wraw[r] = e1 * E2s[t * 4 + j];
                    ++r;
                }
            }
        }
        __syncthreads();
    }
}

__global__ __launch_bounds__(256) void k_g(const float* __restrict__ h,
        const float* __restrict__ wraw, uint16_t* __restrict__ gt) {
    __shared__ float tile[64][65];
    const int bj = blockIdx.x, bf = blockIdx.y;
    const int t = threadIdx.x;
    for (int e = t; e < 4096; e += 256) {
        const int r = e >> 6, c = e & 63;
        const int j = bj * 64 + r;
        tile[r][c] = h[(size_t)j * 256 + bf * 64 + c] * wraw[j];
    }
    __syncthreads();
    for (int e = t; e < 4096; e += 256) {
        const int r = e >> 6, c = e & 63;
        gt[(size_t)(bf * 64 + r) * NN + bj * 64 + c] = f2bf(tile[c][r]);
    }
}

__global__ __launch_bounds__(256) void k_fused(const int* __restrict__ adj,
        const uint16_t* __restrict__ gt, const float* __restrict__ E1,
        const float* __restrict__ E2, float* __restrict__ part,
        float* __restrict__ Sg, int krange) {
    __shared__ __align__(16) uint16_t As[64 * 72];
    __shared__ __align__(16) uint16_t Gs[272 * 72];
    const int ib = blockIdx.x, ks = blockIdx.y;
    const int t = threadIdx.x;
    const int wv = t >> 6, lane = t & 63;
    const int q = lane >> 4, m16 = lane & 15;
    const int i0 = ib * 64, k0 = ks * krange;
    const int ksteps = krange >> 6;
    fx4 acc[4][4];
    #pragma unroll
    for (int a = 0; a < 4; ++a)
        #pragma unroll
        for (int b = 0; b < 4; ++b) acc[a][b] = (fx4){0.f, 0.f, 0.f, 0.f};
    fx4 accS[4];
    #pragma unroll
    for (int a = 0; a < 4; ++a) accS[a] = (fx4){0.f, 0.f, 0.f, 0.f};
    for (int e = t; e < 15 * 72; e += 256) Gs[257 * 72 + e] = 0;
    for (int step = 0; step < ksteps; ++step) {
        const int kk = k0 + step * 64;
        #pragma unroll
        for (int p = 0; p < 4; ++p) {
            const int r = p * 16 + (t >> 4);
            const int c4 = (t & 15) * 4;
            const int4 a = *(const int4*)(adj + (size_t)(i0 + r) * NN + kk + c4);
            uint2 w;
            w.x = (uint32_t)(a.x | (a.y << 16)) * 0x3F80u;
            w.y = (uint32_t)(a.z | (a.w << 16)) * 0x3F80u;
            *(uint2*)(&As[r * 72 + c4]) = w;
        }
        #pragma unroll
        for (int p = 0; p < 8; ++p) {
            const int f = p * 32 + (t >> 3);
            const int ch = (t & 7) * 8;
            const s8v v = *(const s8v*)(gt + (size_t)f * NN + kk + ch);
            *(s8v*)(Gs + f * 72 + ch) = v;
        }
        if (t < 8) {
            const float* e2p = E2 + kk + t * 8;
            uint32_t* dst = (uint32_t*)(&Gs[256 * 72 + t * 8]);
            #pragma unroll
            for (int j = 0; j < 4; ++j)
                dst[j] = (uint32_t)f2bf(e2p[2 * j]) |
                         ((uint32_t)f2bf(e2p[2 * j + 1]) << 16);
        }
        __syncthreads();
        s8v afr[4][2];
        #pragma unroll
        for (int it = 0; it < 4; ++it)
            #pragma unroll
            for (int kh = 0; kh < 2; ++kh)
                afr[it][kh] = *(const s8v*)(As + (it * 16 + m16) * 72 + kh * 32 + q * 8);
        #pragma unroll
        for (int ft = 0; ft < 4; ++ft) {
            #pragma unroll
            for (int kh = 0; kh < 2; ++kh) {
                const s8v bfr = *(const s8v*)(Gs + (wv * 64 + ft * 16 + m16) * 72 + kh * 32 + q * 8);
                #pragma unroll
                for (int it = 0; it < 4; ++it)
                    acc[it][ft] = __builtin_amdgcn_mfma_f32_16x16x32_bf16(
                        afr[it][kh], bfr, acc[it][ft], 0, 0, 0);
            }
        }
        if (wv == 3) {
            #pragma unroll
            for (int kh = 0; kh < 2; ++kh) {
                const s8v bfrS = *(const s8v*)(Gs + (256 + m16) * 72 + kh * 32 + q * 8);
                #pragma unroll
                for (int it = 0; it < 4; ++it)
                    accS[it] = __builtin_amdgcn_mfma_f32_16x16x32_bf16(
                        afr[it][kh], bfrS, accS[it], 0, 0, 0);
            }
        }
        __syncthreads();
    }
    if (wv == 3) {
        float s_local = 0.f;
        #pragma unroll
        for (int it = 0; it < 4; ++it)
            #pragma unroll
            for (int r = 0; r < 4; ++r)
                s_local += accS[it][r] * E1[i0 + it * 16 + q * 4 + r];
        #pragma unroll
        for (int d = 32; d > 0; d >>= 1) s_local += __shfl_down(s_local, d);
        if (lane == 0) atomicAdd(Sg, s_local);
    }
    float* dst = part + (size_t)ks * NN * FDIM;
    #pragma unroll
    for (int it = 0; it < 4; ++it) {
        #pragma unroll
        for (int ft = 0; ft < 4; ++ft) {
            const int f = wv * 64 + ft * 16 + m16;
            #pragma unroll
            for (int r = 0; r < 4; ++r) {
                const int i = i0 + it * 16 + q * 4 + r;
                dst[(size_t)i * FDIM + f] = acc[it][ft][r];
            }
        }
    }
}

__global__ __launch_bounds__(256) void k_out(const float* __restrict__ part,
        const float* __restrict__ Sg, float* __restrict__ out, int nsplit) {
    const int idx = blockIdx.x * 256 + threadIdx.x;
    const float inv = 1.0f / (*Sg);
    fx4 s = {0.f, 0.f, 0.f, 0.f};
    for (int k = 0; k < nsplit; ++k)
        s += *(const fx4*)(part + (size_t)k * NN * FDIM + (size_t)idx * 4);
    fx4 r;
    r[0] = fmaxf(s[0], 0.f) * inv;
    r[1] = fmaxf(s[1], 0.f) * inv;
    r[2] = fmaxf(s[2], 0.f) * inv;
    r[3] = fmaxf(s[3], 0.f) * inv;
    *(fx4*)(out + (size_t)idx * 4) = r;
}

extern "C" void kernel_launch(void* const* d_in, const int* in_sizes, int n_in,
                              void* d_out, int out_size, void* d_ws, size_t ws_size,
                              hipStream_t stream) {
    const float* x     = (const float*)d_in[0];
    const int*   adj   = (const int*)d_in[1];
    const float* W     = (const float*)d_in[2];
    const float* bias  = (const float*)d_in[3];
    const float* att_w = (const float*)d_in[4];
    // att_b (d_in[5]) cancels exactly in the softmax — unused.
    float* out = (float*)d_out;
    char* ws = (char*)d_ws;
    float*    h    = (float*)(ws + 0);                    // 4 MB
    uint16_t* gt   = (uint16_t*)(ws + (size_t)4194304);   // 2 MB
    float*    a1   = (float*)(ws + 6291456);              // 16 KB
    float*    a2   = (float*)(ws + 6307840);              // 16 KB
    float*    E1   = (float*)(ws + 6324224);              // 16 KB
    float*    E2   = (float*)(ws + 6340608);              // 16 KB
    float*    wraw = (float*)(ws + 6356992);              // 16 KB
    float*    Sg   = (float*)(ws + 6373376);              // 256 B
    float*    part = (float*)(ws + 6373632);              // 8 * 4 MB

    const size_t need = (size_t)6373632 + (size_t)8 * NN * FDIM * sizeof(float);
    bool coop_ok = false;
    if (ws_size >= need) {
        void* args[] = {(void*)&x, (void*)&adj, (void*)&W, (void*)&bias,
                        (void*)&att_w, (void*)&h, (void*)&gt, (void*)&a1,
                        (void*)&a2, (void*)&E1, (void*)&E2, (void*)&wraw,
                        (void*)&Sg, (void*)&part, (void*)&out};
        hipError_t e = hipLaunchCooperativeKernel((const void*)k_mega, dim3(512),
                                                  dim3(256), args, 0, stream);
        coop_ok = (e == hipSuccess);
    }
    if (!coop_ok) {
        // fallback: round-3 multi-kernel path
        const size_t avail = (ws_size > 6373632) ? (ws_size - 6373632) : 0;
        int splitk = 1;
        while (splitk < 8 &&
               (size_t)(splitk * 2) * NN * FDIM * sizeof(float) <= avail)
            splitk <<= 1;
        const int krange = NN / splitk;
        k_h    <<<dim3(128, 4), 256, 0, stream>>>(x, W, bias, h);
        k_a    <<<dim3(1024), 256, 0, stream>>>(h, att_w, a1, a2);
        k_prep <<<dim3(1), 1024, 0, stream>>>(a1, a2, adj, E1, E2, wraw, Sg);
        k_g    <<<dim3(64, 4), 256, 0, stream>>>(h, wraw, gt);
        k_fused<<<dim3(64, splitk), 256, 0, stream>>>(adj, gt, E1, E2, part, Sg, krange);
        k_out  <<<dim3(1024), 256, 0, stream>>>(part, Sg, out, splitk);
    }
}

// Round 5
// 152.301 us; speedup vs baseline: 3.0649x; 3.0649x over previous
//
#include <hip/hip_runtime.h>
#include <cstdint>
#include <cstddef>

#define NN 4096
#define FDIM 256

typedef __attribute__((ext_vector_type(4))) float fx4;
typedef __attribute__((ext_vector_type(2))) float fx2;
typedef __attribute__((ext_vector_type(8))) short s8v;

__device__ inline uint16_t f2bf(float f) {
    union { float f; uint32_t u; } v; v.f = f;
    uint32_t u = v.u;
    uint32_t r = (u + 0x7FFFu + ((u >> 16) & 1u)) >> 16;
    return (uint16_t)r;
}

// ---------------- k_h: h = x @ W.T + b, plus a1/a2 chunk partials ----------------
// 32x64 tiles, dbuf + reg prefetch, grid(128,4)=512 -> 2 blocks/CU.
// Epilogue folds the old k_a: a1p[bf][i] = sum_{f in chunk} h[i][f]*w1[f].
__global__ __launch_bounds__(256) void k_h(const float* __restrict__ x,
        const float* __restrict__ W, const float* __restrict__ bias,
        const float* __restrict__ att_w, float* __restrict__ h,
        float* __restrict__ a1p, float* __restrict__ a2p) {
    __shared__ __align__(16) float xs[2][64 * 34];
    __shared__ __align__(16) float wt[2][64 * 68];
    const int bi = blockIdx.x, bf = blockIdx.y;
    const int t = threadIdx.x;
    const int tx = t & 15, ty = t >> 4;
    float acc[2][4] = {};
    float rx[8], rw[16];
    #pragma unroll
    for (int u = 0; u < 8; ++u) {
        const int e = t + 256 * u, r = e >> 6, c = e & 63;
        rx[u] = x[(size_t)(bi * 32 + r) * 256 + c];
    }
    #pragma unroll
    for (int u = 0; u < 16; ++u) {
        const int e = t + 256 * u, r = e >> 6, c = e & 63;
        rw[u] = W[(size_t)(bf * 64 + r) * 256 + c];
    }
    for (int p = 0; p < 4; ++p) {
        float* xb = xs[p & 1];
        float* wb = wt[p & 1];
        #pragma unroll
        for (int u = 0; u < 8; ++u) {
            const int e = t + 256 * u, r = e >> 6, c = e & 63;
            xb[c * 34 + r] = rx[u];
        }
        #pragma unroll
        for (int u = 0; u < 16; ++u) {
            const int e = t + 256 * u, r = e >> 6, c = e & 63;
            const int sw = 8 * ((c & 7) ^ ((c >> 3) & 7));
            wb[c * 68 + (r ^ sw)] = rw[u];
        }
        __syncthreads();
        if (p < 3) {
            const int k0 = (p + 1) * 64;
            #pragma unroll
            for (int u = 0; u < 8; ++u) {
                const int e = t + 256 * u, r = e >> 6, c = e & 63;
                rx[u] = x[(size_t)(bi * 32 + r) * 256 + k0 + c];
            }
            #pragma unroll
            for (int u = 0; u < 16; ++u) {
                const int e = t + 256 * u, r = e >> 6, c = e & 63;
                rw[u] = W[(size_t)(bf * 64 + r) * 256 + k0 + c];
            }
        }
        #pragma unroll 16
        for (int k = 0; k < 64; ++k) {
            const int sw = 8 * ((k & 7) ^ ((k >> 3) & 7));
            const fx2 av = *(const fx2*)(xb + k * 34 + ty * 2);
            const fx4 bv = *(const fx4*)(wb + k * 68 + ((tx * 4) ^ sw));
            #pragma unroll
            for (int u = 0; u < 2; ++u)
                #pragma unroll
                for (int v = 0; v < 4; ++v)
                    acc[u][v] += av[u] * bv[v];
        }
    }
    const fx4 bv = *(const fx4*)(bias + bf * 64 + tx * 4);
    const fx4 w1v = *(const fx4*)(att_w + bf * 64 + tx * 4);
    const fx4 w2v = *(const fx4*)(att_w + 256 + bf * 64 + tx * 4);
    #pragma unroll
    for (int u = 0; u < 2; ++u) {
        const int i = bi * 32 + ty * 2 + u;
        fx4 r;
        float s1 = 0.f, s2 = 0.f;
        #pragma unroll
        for (int v = 0; v < 4; ++v) {
            r[v] = acc[u][v] + bv[v];
            s1 += r[v] * w1v[v];
            s2 += r[v] * w2v[v];
        }
        *(fx4*)(h + (size_t)i * 256 + bf * 64 + tx * 4) = r;
        // reduce across the 16 tx-lanes (aligned 16-lane segments)
        #pragma unroll
        for (int d = 8; d > 0; d >>= 1) {
            s1 += __shfl_down(s1, d, 16);
            s2 += __shfl_down(s2, d, 16);
        }
        if (tx == 0) {
            a1p[bf * NN + i] = s1;
            a2p[bf * NN + i] = s2;
        }
    }
}

// ---- k_prep: reduce a-partials, max/exp -> E1,E2, Sg=0, first-4096-edge scan ----
__global__ __launch_bounds__(1024) void k_prep(const float* __restrict__ a1p,
        const float* __restrict__ a2p, const int* __restrict__ adj,
        float* __restrict__ E1, float* __restrict__ E2,
        float* __restrict__ wraw, float* __restrict__ Sg) {
    __shared__ float E1s[NN];
    __shared__ float E2s[NN];
    __shared__ float red1[16], red2[16];
    __shared__ int wtot[16];
    __shared__ int base_s;
    const int t = threadIdx.x, lane = t & 63, wv = t >> 6;
    fx4 v1 = {0.f, 0.f, 0.f, 0.f}, v2 = {0.f, 0.f, 0.f, 0.f};
    #pragma unroll
    for (int bf = 0; bf < 4; ++bf) {
        v1 += *(const fx4*)(a1p + bf * NN + t * 4);
        v2 += *(const fx4*)(a2p + bf * NN + t * 4);
    }
    float m1 = fmaxf(fmaxf(v1[0], v1[1]), fmaxf(v1[2], v1[3]));
    float m2 = fmaxf(fmaxf(v2[0], v2[1]), fmaxf(v2[2], v2[3]));
    #pragma unroll
    for (int d = 32; d > 0; d >>= 1) {
        m1 = fmaxf(m1, __shfl_down(m1, d));
        m2 = fmaxf(m2, __shfl_down(m2, d));
    }
    if (lane == 0) { red1[wv] = m1; red2[wv] = m2; }
    __syncthreads();
    if (t == 0) {
        float mm1 = -1e30f, mm2 = -1e30f;
        for (int k = 0; k < 16; ++k) {
            mm1 = fmaxf(mm1, red1[k]);
            mm2 = fmaxf(mm2, red2[k]);
        }
        red1[0] = mm1; red2[0] = mm2;
        *Sg = 0.f;
        base_s = 0;
    }
    __syncthreads();
    const float M1 = red1[0], M2 = red2[0];
    fx4 e1v, e2v, z4 = {0.f, 0.f, 0.f, 0.f};
    #pragma unroll
    for (int j = 0; j < 4; ++j) {
        e1v[j] = expf(v1[j] - M1);
        e2v[j] = expf(v2[j] - M2);
    }
    *(fx4*)(E1s + t * 4) = e1v;
    *(fx4*)(E2s + t * 4) = e2v;
    *(fx4*)(E1 + t * 4) = e1v;
    *(fx4*)(E2 + t * 4) = e2v;
    *(fx4*)(wraw + t * 4) = z4;
    __syncthreads();
    for (int row = 0; row < NN; ++row) {
        const int base = base_s;           // uniform
        if (base >= NN) break;             // uniform break
        const int4 a = ((const int4*)(adj + (size_t)row * NN))[t];
        const int vj[4] = {a.x, a.y, a.z, a.w};
        int cnt = 0;
        #pragma unroll
        for (int j = 0; j < 4; ++j) cnt += (vj[j] == 1);
        int inc = cnt;
        #pragma unroll
        for (int d = 1; d < 64; d <<= 1) {
            const int y = __shfl_up(inc, d);
            if (lane >= d) inc += y;
        }
        if (lane == 63) wtot[wv] = inc;
        __syncthreads();                   // B1
        int wbase = 0, total = 0;
        #pragma unroll
        for (int w = 0; w < 16; ++w) {
            const int xw = wtot[w];
            total += xw;
            wbase += (w < wv) ? xw : 0;
        }
        if (t == 0) base_s = base + total;
        int r = base + wbase + inc - cnt;
        if (cnt && r < NN) {
            const float e1 = E1s[row];
            #pragma unroll
            for (int j = 0; j < 4; ++j) {
                if (vj[j] == 1) {
                    if (r < NN) wraw[r] = e1 * E2s[t * 4 + j];
                    ++r;
                }
            }
        }
        __syncthreads();                   // B2
    }
}

// -------- k_g: gt[f][j] = bf16(wraw[j] * h[j][f]); 512 blocks (32j x 64f) --------
__global__ __launch_bounds__(256) void k_g(const float* __restrict__ h,
        const float* __restrict__ wraw, uint16_t* __restrict__ gt) {
    __shared__ float tile[32 * 65];
    const int bj = blockIdx.x, bf = blockIdx.y;   // 128 x 4
    const int j0 = bj * 32, f0 = bf * 64;
    const int t = threadIdx.x;
    #pragma unroll
    for (int p = 0; p < 8; ++p) {
        const int e = t + 256 * p;
        const int jl = e >> 6, fl = e & 63;
        tile[jl * 65 + fl] = h[(size_t)(j0 + jl) * 256 + f0 + fl] * wraw[j0 + jl];
    }
    __syncthreads();
    #pragma unroll
    for (int p = 0; p < 8; ++p) {
        const int e = t + 256 * p;
        const int fl = e >> 5, jl = e & 31;
        gt[(size_t)(f0 + fl) * NN + j0 + jl] = f2bf(tile[jl * 65 + fl]);
    }
}

// -------- k_fused: part = A @ G (bf16 MFMA, split-K) + S via appended E2 column --------
// block: 256 thr (4 waves), tile BM=64 x BN=256, BK=64; wave = 64i x 64f.
// Gs rows 0..255 = gt; row 256 = E2 (bf16); rows 257..271 = 0. Wave 3's extra 16-col
// tile gives C[i][256] = adj_row . E2; epilogue: S += E1[i]*C[i][256].
__global__ __launch_bounds__(256) void k_fused(const int* __restrict__ adj,
        const uint16_t* __restrict__ gt, const float* __restrict__ E1,
        const float* __restrict__ E2, uint16_t* __restrict__ part,
        float* __restrict__ Sg, int krange) {
    __shared__ __align__(16) uint16_t As[64 * 72];
    __shared__ __align__(16) uint16_t Gs[272 * 72];
    const int ib = blockIdx.x, ks = blockIdx.y;
    const int t = threadIdx.x;
    const int wv = t >> 6, lane = t & 63;
    const int q = lane >> 4, m16 = lane & 15;
    const int i0 = ib * 64, k0 = ks * krange;
    const int ksteps = krange >> 6;
    fx4 acc[4][4];
    #pragma unroll
    for (int a = 0; a < 4; ++a)
        #pragma unroll
        for (int b = 0; b < 4; ++b) acc[a][b] = (fx4){0.f, 0.f, 0.f, 0.f};
    fx4 accS[4];
    #pragma unroll
    for (int a = 0; a < 4; ++a) accS[a] = (fx4){0.f, 0.f, 0.f, 0.f};
    for (int e = t; e < 15 * 72; e += 256) Gs[257 * 72 + e] = 0;
    for (int step = 0; step < ksteps; ++step) {
        const int kk = k0 + step * 64;
        #pragma unroll
        for (int p = 0; p < 4; ++p) {
            const int r = p * 16 + (t >> 4);
            const int c4 = (t & 15) * 4;
            const int4 a = *(const int4*)(adj + (size_t)(i0 + r) * NN + kk + c4);
            uint2 w;
            w.x = (uint32_t)(a.x | (a.y << 16)) * 0x3F80u;
            w.y = (uint32_t)(a.z | (a.w << 16)) * 0x3F80u;
            *(uint2*)(&As[r * 72 + c4]) = w;
        }
        #pragma unroll
        for (int p = 0; p < 8; ++p) {
            const int f = p * 32 + (t >> 3);
            const int ch = (t & 7) * 8;
            const s8v v = *(const s8v*)(gt + (size_t)f * NN + kk + ch);
            *(s8v*)(Gs + f * 72 + ch) = v;
        }
        if (t < 8) {
            const float* e2p = E2 + kk + t * 8;
            uint32_t* dst = (uint32_t*)(&Gs[256 * 72 + t * 8]);
            #pragma unroll
            for (int j = 0; j < 4; ++j)
                dst[j] = (uint32_t)f2bf(e2p[2 * j]) |
                         ((uint32_t)f2bf(e2p[2 * j + 1]) << 16);
        }
        __syncthreads();
        s8v afr[4][2];
        #pragma unroll
        for (int it = 0; it < 4; ++it)
            #pragma unroll
            for (int kh = 0; kh < 2; ++kh)
                afr[it][kh] = *(const s8v*)(As + (it * 16 + m16) * 72 + kh * 32 + q * 8);
        #pragma unroll
        for (int ft = 0; ft < 4; ++ft) {
            #pragma unroll
            for (int kh = 0; kh < 2; ++kh) {
                const s8v bfr = *(const s8v*)(Gs + (wv * 64 + ft * 16 + m16) * 72 + kh * 32 + q * 8);
                #pragma unroll
                for (int it = 0; it < 4; ++it)
                    acc[it][ft] = __builtin_amdgcn_mfma_f32_16x16x32_bf16(
                        afr[it][kh], bfr, acc[it][ft], 0, 0, 0);
            }
        }
        if (wv == 3) {
            #pragma unroll
            for (int kh = 0; kh < 2; ++kh) {
                const s8v bfrS = *(const s8v*)(Gs + (256 + m16) * 72 + kh * 32 + q * 8);
                #pragma unroll
                for (int it = 0; it < 4; ++it)
                    accS[it] = __builtin_amdgcn_mfma_f32_16x16x32_bf16(
                        afr[it][kh], bfrS, accS[it], 0, 0, 0);
            }
        }
        __syncthreads();
    }
    if (wv == 3) {
        float s_local = 0.f;
        #pragma unroll
        for (int it = 0; it < 4; ++it)
            #pragma unroll
            for (int r = 0; r < 4; ++r)
                s_local += accS[it][r] * E1[i0 + it * 16 + q * 4 + r];
        #pragma unroll
        for (int d = 32; d > 0; d >>= 1) s_local += __shfl_down(s_local, d);
        if (lane == 0) atomicAdd(Sg, s_local);
    }
    // bf16 partials: 8 partials x 2^-9 relative rounding ~ 1e-8 absolute on out
    uint16_t* dst = part + (size_t)ks * NN * FDIM;
    #pragma unroll
    for (int it = 0; it < 4; ++it) {
        #pragma unroll
        for (int ft = 0; ft < 4; ++ft) {
            const int f = wv * 64 + ft * 16 + m16;
            #pragma unroll
            for (int r = 0; r < 4; ++r) {
                const int i = i0 + it * 16 + q * 4 + r;
                dst[(size_t)i * FDIM + f] = f2bf(acc[it][ft][r]);
            }
        }
    }
}

// -------- k_out: out = relu(sum_k part_k) / S (bf16 partials, 8 f/thread) --------
__global__ __launch_bounds__(256) void k_out(const uint16_t* __restrict__ part,
        const float* __restrict__ Sg, float* __restrict__ out, int nsplit) {
    const size_t idx = ((size_t)blockIdx.x * 256 + threadIdx.x) * 8;
    const float inv = 1.0f / (*Sg);
    float s[8] = {};
    for (int k = 0; k < nsplit; ++k) {
        const s8v v = *(const s8v*)(part + (size_t)k * NN * FDIM + idx);
        #pragma unroll
        for (int j = 0; j < 8; ++j) {
            union { uint32_t u; float f; } cv;
            cv.u = ((uint32_t)(uint16_t)v[j]) << 16;
            s[j] += cv.f;
        }
    }
    fx4 r0, r1;
    #pragma unroll
    for (int j = 0; j < 4; ++j) {
        r0[j] = fmaxf(s[j], 0.f) * inv;
        r1[j] = fmaxf(s[4 + j], 0.f) * inv;
    }
    *(fx4*)(out + idx) = r0;
    *(fx4*)(out + idx + 4) = r1;
}

extern "C" void kernel_launch(void* const* d_in, const int* in_sizes, int n_in,
                              void* d_out, int out_size, void* d_ws, size_t ws_size,
                              hipStream_t stream) {
    const float* x     = (const float*)d_in[0];
    const int*   adj   = (const int*)d_in[1];
    const float* W     = (const float*)d_in[2];
    const float* bias  = (const float*)d_in[3];
    const float* att_w = (const float*)d_in[4];
    // att_b (d_in[5]) cancels exactly in the softmax — unused.
    float* out = (float*)d_out;
    char* ws = (char*)d_ws;
    float*    h    = (float*)(ws + 0);                    // 4 MB
    uint16_t* gt   = (uint16_t*)(ws + (size_t)4194304);   // 2 MB
    float*    a1p  = (float*)(ws + 6291456);              // 64 KB (4 x 4096)
    float*    a2p  = (float*)(ws + 6356992);              // 64 KB
    float*    E1   = (float*)(ws + 6422528);              // 16 KB
    float*    E2   = (float*)(ws + 6438912);              // 16 KB
    float*    wraw = (float*)(ws + 6455296);              // 16 KB
    float*    Sg   = (float*)(ws + 6471680);              // 256 B
    uint16_t* part = (uint16_t*)(ws + 6471936);           // splitk * 2 MB (bf16)

    const size_t avail = (ws_size > 6471936) ? (ws_size - 6471936) : 0;
    int splitk = 1;
    while (splitk < 8 &&
           (size_t)(splitk * 2) * NN * FDIM * sizeof(uint16_t) <= avail)
        splitk <<= 1;
    const int krange = NN / splitk;

    k_h    <<<dim3(128, 4), 256, 0, stream>>>(x, W, bias, att_w, h, a1p, a2p);
    k_prep <<<dim3(1), 1024, 0, stream>>>(a1p, a2p, adj, E1, E2, wraw, Sg);
    k_g    <<<dim3(128, 4), 256, 0, stream>>>(h, wraw, gt);
    k_fused<<<dim3(64, splitk), 256, 0, stream>>>(adj, gt, E1, E2, part, Sg, krange);
    k_out  <<<dim3(512), 256, 0, stream>>>(part, Sg, out, splitk);
}